// Round 8
// baseline (80.343 us; speedup 1.0000x reference)
//
#include <hip/hip_runtime.h>
#include <hip/hip_fp16.h>

#define NB 8
#define NS 1024
#define NH 8

typedef float f2 __attribute__((ext_vector_type(2)));

#if __has_builtin(__builtin_amdgcn_exp2f)
#define EXP2F(x) __builtin_amdgcn_exp2f(x)
#else
#define EXP2F(x) exp2f(x)
#endif

// ---------------------------------------------------------------------------
// Quantum layer collapsed analytically: with c_j = cos(x_j + th_j),
//   meas[0]    = c1*c2*...*c7
//   meas[w>=1] = c0*c1*...*cw
// (CNOT chain = basis permutation; E[(-1)^XOR of independent bits] = product
//  of per-bit expectations.)  q = meas[0:3]/8, k = meas[3:6], v = meas[6:8];
// scores in [-0.375,0.375] -> softmax needs no max subtraction. exp via
// exp2 with log2(e)/8 folded into the q prescale. Verified vs np ref R3-R7.
//
// R5 lesson: no spin grid-barriers on gfx950 (~65 us each).
// R6 lesson: attention loop is LDS-pipe heavy -> 4 s per thread, packed v1.
// R7 lesson: at 2 blocks/CU (8 waves) the loop is LATENCY-bound, not
//            issue-bound -> R8 repartitions to 1024 blocks (4/CU, 16 waves)
//            with same per-CU LDS traffic; slice reduction moved into
//            wave shuffles so LDS fits 4 blocks/CU.
// ---------------------------------------------------------------------------

// K1: block = (bh = blockIdx>>4, chunk = blockIdx&15 -> 64 s-values).
// Stage kv f32 for all 1024 t of this bh into LDS; thread owns 4 s
// (sIdx = tid&15, s-offsets {0,16,32,48}) and 64 t (slice = tid>>4).
// Slice partials: shfl_xor(16,32) within wave, then 4 wave-partials via LDS.
__global__ __launch_bounds__(256, 4) void attn_fused(
        const float* __restrict__ x, const float* __restrict__ theta,
        float* __restrict__ att) {
    __shared__ float4 kvl[NS];                    // (k0,k1,k2,v0) 16 KB
    __shared__ __align__(16) float v1l[NS];       //  4 KB, read as float4
    __shared__ float redS[4][68];                 //  3 x 1.06 KB
    __shared__ float redA[4][68];
    __shared__ float redB[4][68];

    const int tid = threadIdx.x;
    const int bh = blockIdx.x >> 4;
    const int chunk = blockIdx.x & 15;
    const int b = bh >> 3, h = bh & 7;
    const int s0 = chunk * 64;

    float th[8];
#pragma unroll
    for (int j = 0; j < 8; ++j) th[j] = theta[j];

    // ---- stage kv for all 1024 t ----
#pragma unroll
    for (int i = 0; i < 4; ++i) {
        int t = tid + i * 256;
        const float4* xp = (const float4*)(x + (((size_t)(b * NS + t)) << 6) + h * 8);
        float4 lo = xp[0], hi = xp[1];
        float c0 = __cosf(lo.x + th[0]);
        float c1 = __cosf(lo.y + th[1]);
        float c2 = __cosf(lo.z + th[2]);
        float c3 = __cosf(lo.w + th[3]);
        float c4 = __cosf(hi.x + th[4]);
        float c5 = __cosf(hi.y + th[5]);
        float c6 = __cosf(hi.z + th[6]);
        float c7 = __cosf(hi.w + th[7]);
        float m3 = ((c0 * c1) * c2) * c3;
        float m4 = m3 * c4;
        float m5 = m4 * c5;
        float m6 = m5 * c6;
        kvl[t] = make_float4(m3, m4, m5, m6);
        v1l[t] = m6 * c7;
    }

    // ---- q for this thread's 4 s (prescaled by log2e/8) ----
    const float QSC = 0.125f * 1.44269504088896f;
    const int sIdx = tid & 15;
    const int slice = tid >> 4;                   // 0..15
    f2 qx[2], qy[2], qz[2];
#pragma unroll
    for (int p = 0; p < 2; ++p)
#pragma unroll
        for (int i = 0; i < 2; ++i) {
            int s = s0 + sIdx + (p * 2 + i) * 16;
            const float4* xp = (const float4*)(x + (((size_t)(b * NS + s)) << 6) + h * 8);
            float4 lo = xp[0], hi = xp[1];
            float c0 = __cosf(lo.x + th[0]);
            float c1 = __cosf(lo.y + th[1]);
            float c2 = __cosf(lo.z + th[2]);
            float c3 = __cosf(lo.w + th[3]);
            float c4 = __cosf(hi.x + th[4]);
            float c5 = __cosf(hi.y + th[5]);
            float c6 = __cosf(hi.z + th[6]);
            float c7 = __cosf(hi.w + th[7]);
            float m1 = c0 * c1;
            float m2 = m1 * c2;
            float m0 = ((c1 * c2) * (c3 * c4)) * ((c5 * c6) * c7);
            qx[p][i] = m0 * QSC;
            qy[p][i] = m1 * QSC;
            qz[p][i] = m2 * QSC;
        }
    __syncthreads();

    // ---- inner loop: 64 t in 16 groups of 4; 4 s per thread ----
    f2 sum[2] = {{0.f, 0.f}, {0.f, 0.f}};
    f2 A0[2]  = {{0.f, 0.f}, {0.f, 0.f}};
    f2 A1[2]  = {{0.f, 0.f}, {0.f, 0.f}};
    const int t0 = slice * 64;
    const float4* v1g4 = (const float4*)v1l;
#pragma unroll 4
    for (int g = 0; g < 16; ++g) {
        float4 v14 = v1g4[(t0 >> 2) + g];
        float4 kv0 = kvl[t0 + g * 4 + 0];
        float4 kv1 = kvl[t0 + g * 4 + 1];
        float4 kv2 = kvl[t0 + g * 4 + 2];
        float4 kv3 = kvl[t0 + g * 4 + 3];
        const float vv[4] = {v14.x, v14.y, v14.z, v14.w};
        const float4 kvs[4] = {kv0, kv1, kv2, kv3};
#pragma unroll
        for (int j = 0; j < 4; ++j) {
            float4 kv = kvs[j];
            float v1 = vv[j];
#pragma unroll
            for (int p = 0; p < 2; ++p) {
                f2 d = qx[p] * kv.x;
                d += qy[p] * kv.y;
                d += qz[p] * kv.z;
                f2 e = {EXP2F(d.x), EXP2F(d.y)};
                sum[p] += e;
                A0[p] += e * kv.w;
                A1[p] += e * v1;
            }
        }
    }

    // ---- in-wave butterfly over the 4 slices sharing this wave ----
#pragma unroll
    for (int m = 16; m <= 32; m <<= 1) {
#pragma unroll
        for (int p = 0; p < 2; ++p) {
            sum[p].x += __shfl_xor(sum[p].x, m, 64);
            sum[p].y += __shfl_xor(sum[p].y, m, 64);
            A0[p].x  += __shfl_xor(A0[p].x, m, 64);
            A0[p].y  += __shfl_xor(A0[p].y, m, 64);
            A1[p].x  += __shfl_xor(A1[p].x, m, 64);
            A1[p].y  += __shfl_xor(A1[p].y, m, 64);
        }
    }
    const int w = tid >> 6;                       // wave 0..3
    if ((tid & 63) < 16) {
#pragma unroll
        for (int p = 0; p < 2; ++p)
#pragma unroll
            for (int i = 0; i < 2; ++i) {
                int sl = sIdx + (p * 2 + i) * 16;
                redS[w][sl] = (i == 0) ? sum[p].x : sum[p].y;
                redA[w][sl] = (i == 0) ? A0[p].x : A0[p].y;
                redB[w][sl] = (i == 0) ? A1[p].x : A1[p].y;
            }
    }
    __syncthreads();

    if (tid < 64) {
        float S = redS[0][tid] + redS[1][tid] + redS[2][tid] + redS[3][tid];
        float A = redA[0][tid] + redA[1][tid] + redA[2][tid] + redA[3][tid];
        float B = redB[0][tid] + redB[1][tid] + redB[2][tid] + redB[3][tid];
        float inv = 1.0f / S;
        int s = s0 + tid;
        float* o = att + ((size_t)(b * NS + s) * 16) + h * 2;
        o[0] = A * inv;
        o[1] = B * inv;
    }
}

// K2: (8192,16) @ W^T + bias -> (8192,64). 512 blocks x 16 rows.
__global__ __launch_bounds__(256, 2) void proj_kernel(
        const float* __restrict__ att, const float* __restrict__ W,
        const float* __restrict__ bias, float* __restrict__ out) {
    __shared__ float WtL[16 * 65];        // Wt[j*65+e] = W[e*16+j], padded
    __shared__ float biasL[64];
    __shared__ float rowsL[16 * 16];
    const int tid = threadIdx.x;
    const int rbase = blockIdx.x * 16;

    for (int i = tid; i < 1024; i += 256)
        WtL[(i & 15) * 65 + (i >> 4)] = W[i];
    if (tid < 64) biasL[tid] = bias[tid];
    if (tid < 256) rowsL[tid] = att[(size_t)rbase * 16 + tid];
    __syncthreads();

    const int e = tid & 63, rr = tid >> 6;
#pragma unroll
    for (int p = 0; p < 4; ++p) {
        int row = p * 4 + rr;
        float acc = biasL[e];
#pragma unroll
        for (int j = 0; j < 16; ++j)
            acc = fmaf(rowsL[row * 16 + j], WtL[j * 65 + e], acc);
        out[(((size_t)(rbase + row)) << 6) + e] = acc;
    }
}

// ---------------------------------------------------------------------------
// Fallback (R3, proven): fully fused, no workspace. Used only if ws too small.
// ---------------------------------------------------------------------------
#define NPAD 1028
#define SPB 32
__global__ __launch_bounds__(256) void fused_kernel(const float* __restrict__ x,
                                                    const float* __restrict__ theta,
                                                    const float* __restrict__ W,
                                                    const float* __restrict__ bias,
                                                    float* __restrict__ out) {
    __shared__ __half2 kvA[NH][NPAD];
    __shared__ __half2 kvB[NH][NPAD];
    __shared__ __half  kvC[NH][NPAD];
    __shared__ float   attl[SPB][17];
    __shared__ float   Wt[16][64];
    __shared__ float   bl[64];

    const int tid = threadIdx.x;
    const int b = blockIdx.x >> 5;
    const int chunk = blockIdx.x & 31;

    float th[8];
#pragma unroll
    for (int j = 0; j < 8; ++j) th[j] = theta[j];

    for (int i = tid; i < 1024; i += 256) Wt[i & 15][i >> 4] = W[i];
    if (tid < 64) bl[tid] = bias[tid];

    for (int i = 0; i < 32; ++i) {
        int r = tid + (i << 8);
        int h = r & 7, t = r >> 3;
        const float4* xp = (const float4*)(x + (((size_t)(b * NS + t)) << 6) + h * 8);
        float4 lo = xp[0], hi = xp[1];
        float c0 = __cosf(lo.x + th[0]);
        float c1 = __cosf(lo.y + th[1]);
        float c2 = __cosf(lo.z + th[2]);
        float c3 = __cosf(lo.w + th[3]);
        float c4 = __cosf(hi.x + th[4]);
        float c5 = __cosf(hi.y + th[5]);
        float c6 = __cosf(hi.z + th[6]);
        float c7 = __cosf(hi.w + th[7]);
        float m3 = ((c0 * c1) * c2) * c3;
        float m4 = m3 * c4;
        float m5 = m4 * c5;
        float m6 = m5 * c6;
        float m7 = m6 * c7;
        kvA[h][t] = __floats2half2_rn(m3, m4);
        kvB[h][t] = __floats2half2_rn(m5, m6);
        kvC[h][t] = __float2half_rn(m7);
    }
    __syncthreads();

    {
        const int h = tid >> 5;
        const int sl = tid & 31;
        const int sg = chunk * SPB + sl;
        const float4* xp = (const float4*)(x + (((size_t)(b * NS + sg)) << 6) + h * 8);
        float4 lo = xp[0], hi = xp[1];
        float c0 = __cosf(lo.x + th[0]);
        float c1 = __cosf(lo.y + th[1]);
        float c2 = __cosf(lo.z + th[2]);
        float c3 = __cosf(lo.w + th[3]);
        float c4 = __cosf(hi.x + th[4]);
        float c5 = __cosf(hi.y + th[5]);
        float c6 = __cosf(hi.z + th[6]);
        float c7 = __cosf(hi.w + th[7]);
        float m1 = c0 * c1;
        float m2 = m1 * c2;
        float m0 = ((c1 * c2) * (c3 * c4)) * ((c5 * c6) * c7);
        float q0 = m0 * 0.125f, q1 = m1 * 0.125f, q2 = m2 * 0.125f;

        float sum = 0.f, a0 = 0.f, a1 = 0.f;
#pragma unroll 4
        for (int t = 0; t < NS; ++t) {
            float2 kk = __half22float2(kvA[h][t]);
            float2 kv = __half22float2(kvB[h][t]);
            float v1 = __half2float(kvC[h][t]);
            float sc = q0 * kk.x + q1 * kk.y + q2 * kv.x;
            float e = __expf(sc);
            sum += e;
            a0 += e * kv.y;
            a1 += e * v1;
        }
        float inv = 1.0f / sum;
        attl[sl][h * 2] = a0 * inv;
        attl[sl][h * 2 + 1] = a1 * inv;
    }
    __syncthreads();

    {
        const int e = tid & 63;
        const int rr = tid >> 6;
#pragma unroll
        for (int i = 0; i < 8; ++i) {
            int sl = rr * 8 + i;
            float acc = bl[e];
#pragma unroll
            for (int j = 0; j < 16; ++j)
                acc += attl[sl][j] * Wt[j][e];
            int sg = chunk * SPB + sl;
            out[(((size_t)(b * NS + sg)) << 6) + e] = acc;
        }
    }
}

extern "C" void kernel_launch(void* const* d_in, const int* in_sizes, int n_in,
                              void* d_out, int out_size, void* d_ws, size_t ws_size,
                              hipStream_t stream) {
    const float* x     = (const float*)d_in[0];
    const float* theta = (const float*)d_in[1];
    const float* W     = (const float*)d_in[2];
    const float* bias  = (const float*)d_in[3];
    float* out = (float*)d_out;

    if (ws_size >= (size_t)NB * NS * 16 * sizeof(float)) {
        float* att = (float*)d_ws;          // 8192 x 16 f32 (512 KB)
        attn_fused<<<dim3(NB * NH * 16), dim3(256), 0, stream>>>(x, theta, att);
        proj_kernel<<<dim3(NB * NS / 16), dim3(256), 0, stream>>>(att, W, bias, out);
    } else {
        fused_kernel<<<dim3(NB * (NS / SPB)), dim3(256), 0, stream>>>(x, theta, W, bias, out);
    }
}